// Round 1
// baseline (336.264 us; speedup 1.0000x reference)
//
#include <hip/hip_runtime.h>
#include <stdint.h>

// Problem constants
#define B_   2
#define S_   2048      // SQ == SK
#define H_   1024
#define NH_  16
#define D_   64
#define KC_  3072      // KS*H = conv GEMM K-dim

typedef __attribute__((ext_vector_type(8))) short  short8;   // 8 x bf16 bits (4 VGPRs)
typedef __attribute__((ext_vector_type(4))) float  floatx4;  // MFMA C/D

typedef __attribute__((address_space(1))) const void gas_void;
typedef __attribute__((address_space(3))) void       las_void;

// async 16B global->LDS; LDS dest must be wave-uniform base + lane*16.
__device__ __forceinline__ void gld16(const void* g, void* l) {
    __builtin_amdgcn_global_load_lds((gas_void*)g, (las_void*)l, 16, 0, 0);
}

__device__ __forceinline__ unsigned short f2bf(float f) {
    union { float f; unsigned u; } v; v.f = f;
    unsigned r = v.u + 0x7fffu + ((v.u >> 16) & 1u);   // RNE
    return (unsigned short)(r >> 16);
}

// ---------------------------------------------------------------------------
// 1) x [B,2048,1024] f32  ->  xpad [B,2050,1024] bf16 with zero rows at 0,2049
// ---------------------------------------------------------------------------
__global__ __launch_bounds__(256) void k_pad_convert(const float* __restrict__ src,
                                                     unsigned short* __restrict__ dst) {
    int gid = blockIdx.x * 256 + threadIdx.x;
    int vid = gid * 4;
    if (vid >= B_ * 2050 * 1024) return;
    int row = vid >> 10;
    int b   = (row >= 2050) ? 1 : 0;
    int r   = row - b * 2050;
    int h   = vid & 1023;
    unsigned short o0 = 0, o1 = 0, o2 = 0, o3 = 0;
    if (r != 0 && r != 2049) {
        const float4 f = *(const float4*)(src + ((b * 2048 + r - 1) << 10) + h);
        o0 = f2bf(f.x); o1 = f2bf(f.y); o2 = f2bf(f.z); o3 = f2bf(f.w);
    }
    ushort4 o; o.x = o0; o.y = o1; o.z = o2; o.w = o3;
    *(ushort4*)(dst + vid) = o;
}

// ---------------------------------------------------------------------------
// 2) W [R][C] f32 -> Wt [C][R] bf16
// ---------------------------------------------------------------------------
__global__ void k_transpose_bf16(const float* __restrict__ src,
                                 unsigned short* __restrict__ dst, int R, int C) {
    __shared__ float t[32][33];
    int c0 = blockIdx.x * 32, r0 = blockIdx.y * 32;
    int tx = threadIdx.x, ty = threadIdx.y;           // (32,8)
#pragma unroll
    for (int k = 0; k < 4; ++k)
        t[ty + k * 8][tx] = src[(long)(r0 + ty + k * 8) * C + c0 + tx];
    __syncthreads();
#pragma unroll
    for (int k = 0; k < 4; ++k)
        dst[(long)(c0 + ty + k * 8) * R + r0 + tx] = f2bf(t[tx][ty + k * 8]);
}

// ---------------------------------------------------------------------------
// 3) Conv-as-GEMM, 256x256 tile, 8 waves (2Mx4N), BK=64, 48 K-steps.
//    4-phase-per-K-tile counted-vmcnt schedule (T3+T4+T5; m201-style):
//      - K-halves (kk=0/1, 32 cols) are the staging unit: 16 KB = 2 gld16/thr.
//      - phase p: {ds_read frags, issue 1 half-tile prefetch, barrier,
//                  lgkmcnt(0), setprio(1), 16 MFMA, setprio(0), barrier};
//        vmcnt(10) before the P2/P4 end-barrier (never 0 in the loop):
//        steady state = 14 loads in flight, each wait retires exactly the two
//        half-tiles consumed two phases later.
//      - slot liveness: A.k0 read P1/P2 -> rewritten P3(+2 tiles); B.k0 read
//        P1 (to regs) -> rewritten P2; A.k1 read P3/P4 -> rewritten next-P1;
//        B.k1 read P3 -> rewritten P4. Always a barrier between last read
//        and the overwriting issue.
//    Conv shift folds into a flat 64*kt source offset for A and B (row shift
//    t*1024 == one col-slice), so the K-loop is uniform over kt=0..47.
//    LDS swizzle: 16B chunk (row r, k-chunk cp) at p = 4r + (cp^((r>>1)&3));
//    ds_read_b128 frag pattern hits 8 distinct slots/16 lanes => 2-way (free).
//    Inverse swizzle applied on the global source address (linear LDS dest).
// ---------------------------------------------------------------------------
__global__ __launch_bounds__(512, 2) void k_conv_gemm(
    const unsigned short* __restrict__ xq, const unsigned short* __restrict__ xs,
    const unsigned short* __restrict__ Wqt, const unsigned short* __restrict__ Wkt,
    const unsigned short* __restrict__ Wvt,
    const float* __restrict__ bq, const float* __restrict__ bk, const float* __restrict__ bv,
    unsigned short* __restrict__ Qo, unsigned short* __restrict__ Ko,
    unsigned short* __restrict__ Vo) {
    int z = blockIdx.z;
    const unsigned short* X = (z == 0) ? xq : xs;
    const unsigned short* W = (z == 0) ? Wqt : (z == 1 ? Wkt : Wvt);
    const float* bias = (z == 0) ? bq : (z == 1 ? bk : bv);

    // [buf][khalf]: 256 rows x 32 cols bf16 = 16 KB each => 128 KB total
    __shared__ unsigned short Al[2][2][256 * 32];
    __shared__ unsigned short Bl[2][2][256 * 32];

    int n0 = blockIdx.x * 256, m0 = blockIdx.y * 256;
    int b = m0 >> 11;
    int tid = threadIdx.x, lane = tid & 63, w = tid >> 6;
    int quad = lane >> 4, l15 = lane & 15;
    int wm = w >> 2, wn = w & 3;              // 2 x 4 waves, wave tile 128x64

    floatx4 acc[8][4];
#pragma unroll
    for (int i = 0; i < 8; ++i)
#pragma unroll
        for (int j = 0; j < 4; ++j) acc[i][j] = (floatx4){0.f, 0.f, 0.f, 0.f};

    // xpad row for output row s (batch b) is b*2050 + s + t = m + 2b + t
    const unsigned short* Xb = X + (m0 + 2 * b) * 1024;

    // Staging: LDS chunk e (16B) holds source (row r = e>>2,
    // k-chunk cp = (e&3) ^ ((e>>3)&3)) -- inverse of the read swizzle.
    int e0 = tid, e1 = 512 + tid;
    int ra0 = e0 >> 2, ca0 = (e0 & 3) ^ ((e0 >> 3) & 3);
    int ra1 = e1 >> 2, ca1 = (e1 & 3) ^ ((e1 >> 3) & 3);
    const unsigned short* aS0 = Xb + ra0 * 1024 + ca0 * 8;
    const unsigned short* aS1 = Xb + ra1 * 1024 + ca1 * 8;
    const unsigned short* bS0 = W + (long)(n0 + ra0) * KC_ + ca0 * 8;
    const unsigned short* bS1 = W + (long)(n0 + ra1) * KC_ + ca1 * 8;
    int ld0 = tid * 16, ld1 = (512 + tid) * 16;

    auto stA = [&](int kt, int kh) {           // stage A half (kt, kh): 2 loads/thr
        int o = kt * 64 + kh * 32;             // shift t folds into 64*kt
        char* d = (char*)Al + (((kt & 1) * 2 + kh) << 14);
        gld16(aS0 + o, d + ld0);
        gld16(aS1 + o, d + ld1);
    };
    auto stB = [&](int kt, int kh) {
        int o = kt * 64 + kh * 32;
        char* d = (char*)Bl + (((kt & 1) * 2 + kh) << 14);
        gld16(bS0 + o, d + ld0);
        gld16(bS1 + o, d + ld1);
    };

    // compute-side LDS addressing: (r>>1)&3 == (l15>>1)&3 for all frag rows,
    // so the swizzle term is a per-lane constant.
    int xsw = (quad ^ ((l15 >> 1) & 3)) * 16;
    const char* ldsAb = (const char*)Al + wm * 8192 + l15 * 64 + xsw;
    const char* ldsBb = (const char*)Bl + wn * 4096 + l15 * 64 + xsw;

#define LDA(BUF, KK, I) (*(const short8*)(ldsAb + (((BUF) * 2 + (KK)) << 14) + (I) * 1024))
#define LDB(BUF, KK, J) (*(const short8*)(ldsBb + (((BUF) * 2 + (KK)) << 14) + (J) * 1024))
#define PH_MFMA(IH) \
    __builtin_amdgcn_s_setprio(1); \
    _Pragma("unroll") \
    for (int ii = 0; ii < 4; ++ii) \
        _Pragma("unroll") \
        for (int j = 0; j < 4; ++j) \
            acc[(IH) * 4 + ii][j] = __builtin_amdgcn_mfma_f32_16x16x32_bf16( \
                af[ii], bfr[j], acc[(IH) * 4 + ii][j], 0, 0, 0); \
    __builtin_amdgcn_s_setprio(0);
#define BARX() __builtin_amdgcn_s_barrier()
#define LGKM0() asm volatile("s_waitcnt lgkmcnt(0)" ::: "memory")
#define VM10()  asm volatile("s_waitcnt vmcnt(10)" ::: "memory")

    // prologue: prime 7 half-tiles (= steady-state issue stream order)
    stB(0, 0); stA(0, 0); stB(0, 1); stA(0, 1); stB(1, 0); stA(1, 0); stB(1, 1);
    VM10();     // retires B.k0(0), A.k0(0) -- needed by tile0.P1
    BARX();

#define TILE(KT, BUF) do { \
    short8 af[4], bfr[4]; \
    /* P1: kk=0, i0..3; prefetch A.k1(KT+1) */ \
    bfr[0] = LDB(BUF, 0, 0); bfr[1] = LDB(BUF, 0, 1); bfr[2] = LDB(BUF, 0, 2); bfr[3] = LDB(BUF, 0, 3); \
    af[0] = LDA(BUF, 0, 0); af[1] = LDA(BUF, 0, 1); af[2] = LDA(BUF, 0, 2); af[3] = LDA(BUF, 0, 3); \
    stA((KT) + 1, 1); \
    BARX(); LGKM0(); \
    PH_MFMA(0) \
    BARX(); \
    /* P2: kk=0, i4..7 (B reused in regs); prefetch B.k0(KT+2) */ \
    af[0] = LDA(BUF, 0, 4); af[1] = LDA(BUF, 0, 5); af[2] = LDA(BUF, 0, 6); af[3] = LDA(BUF, 0, 7); \
    stB((KT) + 2, 0); \
    BARX(); LGKM0(); \
    PH_MFMA(1) \
    VM10(); /* retires B.k1(KT), A.k1(KT) -- needed by P3 */ \
    BARX(); \
    /* P3: kk=1, i0..3; prefetch A.k0(KT+2) */ \
    bfr[0] = LDB(BUF, 1, 0); bfr[1] = LDB(BUF, 1, 1); bfr[2] = LDB(BUF, 1, 2); bfr[3] = LDB(BUF, 1, 3); \
    af[0] = LDA(BUF, 1, 0); af[1] = LDA(BUF, 1, 1); af[2] = LDA(BUF, 1, 2); af[3] = LDA(BUF, 1, 3); \
    stA((KT) + 2, 0); \
    BARX(); LGKM0(); \
    PH_MFMA(0) \
    BARX(); \
    /* P4: kk=1, i4..7; prefetch B.k1(KT+2) */ \
    af[0] = LDA(BUF, 1, 4); af[1] = LDA(BUF, 1, 5); af[2] = LDA(BUF, 1, 6); af[3] = LDA(BUF, 1, 7); \
    stB((KT) + 2, 1); \
    BARX(); LGKM0(); \
    PH_MFMA(1) \
    VM10(); /* retires B.k0(KT+1), A.k0(KT+1) -- needed by next P1 */ \
    BARX(); \
} while (0)

    for (int kt = 0; kt < 46; kt += 2) {   // TILE(45) issues for 46/47 only
        TILE(kt, 0);
        TILE(kt + 1, 1);
    }

    // tail: tiles 46,47. All stages already in flight except A.k1(47).
    // One full drain near the end; then pure reads -> no barriers needed.
    stA(47, 1);
    asm volatile("s_waitcnt vmcnt(0)" ::: "memory");
    BARX();
    {
        short8 af[4], bfr[4];
#define TAILK(BUF, KK) \
        bfr[0] = LDB(BUF, KK, 0); bfr[1] = LDB(BUF, KK, 1); bfr[2] = LDB(BUF, KK, 2); bfr[3] = LDB(BUF, KK, 3); \
        af[0] = LDA(BUF, KK, 0); af[1] = LDA(BUF, KK, 1); af[2] = LDA(BUF, KK, 2); af[3] = LDA(BUF, KK, 3); \
        PH_MFMA(0) \
        af[0] = LDA(BUF, KK, 4); af[1] = LDA(BUF, KK, 5); af[2] = LDA(BUF, KK, 6); af[3] = LDA(BUF, KK, 7); \
        PH_MFMA(1)
        TAILK(0, 0)
        TAILK(0, 1)
        TAILK(1, 0)
        TAILK(1, 1)
#undef TAILK
    }

    // epilogue: C/D layout col=lane&15, row=quad*4+reg
#pragma unroll
    for (int j = 0; j < 4; ++j) {
        int n = n0 + wn * 64 + j * 16 + l15;
        float bb = bias[n];
        int nh = n >> 6, d = n & 63;
#pragma unroll
        for (int i = 0; i < 8; ++i) {
            int srow = (m0 & 2047) + wm * 128 + i * 16 + quad * 4;
#pragma unroll
            for (int r = 0; r < 4; ++r) {
                float v = acc[i][j][r] + bb;
                int s = srow + r;
                if (z == 0)
                    Qo[((b * NH_ + nh) * 2048 + s) * 64 + d] = f2bf(v * 0.125f);
                else if (z == 1)
                    Ko[((b * NH_ + nh) * 2048 + s) * 64 + d] = f2bf(v);
                else
                    Vo[((b * NH_ + nh) * 64 + d) * 2048 + s] = f2bf(v);
            }
        }
    }
#undef TILE
#undef LDA
#undef LDB
#undef PH_MFMA
#undef BARX
#undef LGKM0
#undef VM10
}

// ---------------------------------------------------------------------------
// 4) Flash attention (known-good; untouched this round so it surfaces in the
//    profile with counters before optimizing).
// ---------------------------------------------------------------------------
__global__ __launch_bounds__(256) void k_flash(
    const unsigned short* __restrict__ Q, const unsigned short* __restrict__ K,
    const unsigned short* __restrict__ Vt, const float* __restrict__ mask,
    unsigned short* __restrict__ Ao) {
    __shared__ unsigned short Ul[128 * 136];   // 34816 B
    __shared__ unsigned short Vl[64 * 128];    // 16384 B

    int tid = threadIdx.x, w = tid >> 6, lane = tid & 63;
    int quad = lane >> 4, l15 = lane & 15;
    int bh = blockIdx.y;
    int b = bh >> 4, nh = bh & 15;
    int q0 = blockIdx.x * 128, wq = w * 32;

    short8 qf[2][2];
#pragma unroll
    for (int i = 0; i < 2; ++i)
#pragma unroll
        for (int kk = 0; kk < 2; ++kk)
            qf[i][kk] = *(const short8*)(Q + ((bh * 2048 + q0 + wq + i * 16 + l15) << 6) + kk * 32 + quad * 8);

    floatx4 oacc[2][4];
    float rsum[2][4];
#pragma unroll
    for (int i = 0; i < 2; ++i) {
#pragma unroll
        for (int j = 0; j < 4; ++j) oacc[i][j] = (floatx4){0.f, 0.f, 0.f, 0.f};
#pragma unroll
        for (int r = 0; r < 4; ++r) rsum[i][r] = 0.f;
    }
    const float* maskb = mask + b * S_;

    for (int kt = 0; kt < 16; ++kt) {
        int k0 = kt * 128;
#pragma unroll
        for (int it = 0; it < 4; ++it) {
            int e  = (it * 256 + tid) * 8;
            int kl = e >> 6;
            int c  = ((e >> 3) & 7) ^ (kl & 7);
            gld16(K + (bh * 2048 + k0 + kl) * 64 + c * 8, (char*)Ul + e * 2);
            int dl = e >> 7;
            int cp = (e >> 3) & 15;
            int c2 = (cp & 8) | ((cp ^ dl) & 7);
            gld16(Vt + (bh * 64 + dl) * 2048 + k0 + c2 * 8, (char*)Vl + e * 2);
        }
        __syncthreads();

        // S = Q K^T  (wave: 32 q-rows x 128 keys)
        floatx4 sacc[2][8];
#pragma unroll
        for (int i = 0; i < 2; ++i)
#pragma unroll
            for (int j = 0; j < 8; ++j) sacc[i][j] = (floatx4){0.f, 0.f, 0.f, 0.f};
#pragma unroll
        for (int j = 0; j < 8; ++j) {
            int kl = j * 16 + l15;
            int cp0 = (0 * 4 + quad) ^ (kl & 7);
            short8 bf0 = *(const short8*)(Ul + kl * 64 + cp0 * 8);
            int cp1 = (1 * 4 + quad) ^ (kl & 7);
            short8 bf1 = *(const short8*)(Ul + kl * 64 + cp1 * 8);
#pragma unroll
            for (int i = 0; i < 2; ++i) {
                sacc[i][j] = __builtin_amdgcn_mfma_f32_16x16x32_bf16(qf[i][0], bf0, sacc[i][j], 0, 0, 0);
                sacc[i][j] = __builtin_amdgcn_mfma_f32_16x16x32_bf16(qf[i][1], bf1, sacc[i][j], 0, 0, 0);
            }
        }
        __syncthreads();   // all waves done reading K-tile before P overwrites Ul

        // P = exp(S + mask*-1e9)
#pragma unroll
        for (int j = 0; j < 8; ++j) {
            float mv = maskb[k0 + j * 16 + l15] * (-1e9f);
#pragma unroll
            for (int i = 0; i < 2; ++i) {
                int row = wq + i * 16 + quad * 4;
#pragma unroll
                for (int r = 0; r < 4; ++r) {
                    float p = __expf(sacc[i][j][r] + mv);
                    rsum[i][r] += p;
                    Ul[(row + r) * 136 + j * 16 + l15] = f2bf(p);
                }
            }
        }
        // no barrier: each wave reads only its own P rows

        // O += P V
#pragma unroll
        for (int kk = 0; kk < 4; ++kk) {
            short8 af[2], bv4[4];
#pragma unroll
            for (int i = 0; i < 2; ++i)
                af[i] = *(const short8*)(Ul + (wq + i * 16 + l15) * 136 + kk * 32 + quad * 8);
#pragma unroll
            for (int j2 = 0; j2 < 4; ++j2) {
                int dl = j2 * 16 + l15;
                int c  = kk * 4 + quad;
                int cp = (c & 8) | ((c ^ dl) & 7);
                bv4[j2] = *(const short8*)(Vl + dl * 128 + cp * 8);
            }
#pragma unroll
            for (int i = 0; i < 2; ++i)
#pragma unroll
                for (int j2 = 0; j2 < 4; ++j2)
                    oacc[i][j2] = __builtin_amdgcn_mfma_f32_16x16x32_bf16(af[i], bv4[j2], oacc[i][j2], 0, 0, 0);
        }
        __syncthreads();
    }

#pragma unroll
    for (int i = 0; i < 2; ++i)
#pragma unroll
        for (int r = 0; r < 4; ++r) {
            float v = rsum[i][r];
            v += __shfl_xor(v, 1); v += __shfl_xor(v, 2);
            v += __shfl_xor(v, 4); v += __shfl_xor(v, 8);
            rsum[i][r] = 1.0f / v;
        }

#pragma unroll
    for (int i = 0; i < 2; ++i)
#pragma unroll
        for (int j2 = 0; j2 < 4; ++j2)
#pragma unroll
            for (int r = 0; r < 4; ++r) {
                int qrow = q0 + wq + i * 16 + quad * 4 + r;
                int hcol = nh * 64 + j2 * 16 + l15;
                Ao[(b * 2048 + qrow) * 1024 + hcol] = f2bf(oacc[i][j2][r] * rsum[i][r]);
            }
}

// ---------------------------------------------------------------------------
// 5) Output projection, double-buffered pipeline. Tile 128x128, K=1024.
// ---------------------------------------------------------------------------
__global__ __launch_bounds__(256) void k_proj_gemm(
    const unsigned short* __restrict__ A, const unsigned short* __restrict__ Wt,
    const float* __restrict__ bo, float* __restrict__ out) {
    __shared__ unsigned short Al[2][128 * 64];
    __shared__ unsigned short Bl[2][128 * 64];

    int n0 = blockIdx.x * 128, m0 = blockIdx.y * 128;
    int tid = threadIdx.x, lane = tid & 63, w = tid >> 6;
    int quad = lane >> 4, l15 = lane & 15;
    int wm = w >> 1, wn = w & 1;

    floatx4 acc[4][4];
#pragma unroll
    for (int i = 0; i < 4; ++i)
#pragma unroll
        for (int j = 0; j < 4; ++j) acc[i][j] = (floatx4){0.f, 0.f, 0.f, 0.f};

    int eoff[4], aoff[4], boff[4];
#pragma unroll
    for (int it = 0; it < 4; ++it) {
        int e  = (it * 256 + tid) * 8;
        int rl = e >> 6;
        int c  = ((e >> 3) & 7) ^ (rl & 7);
        eoff[it] = e;
        aoff[it] = (m0 + rl) * 1024 + c * 8;
        boff[it] = (n0 + rl) * 1024 + c * 8;
    }

    auto stage = [&](int buf, int k0) {
#pragma unroll
        for (int it = 0; it < 4; ++it) {
            gld16(A + aoff[it] + k0, (char*)Al[buf] + eoff[it] * 2);
            gld16(Wt + boff[it] + k0, (char*)Bl[buf] + eoff[it] * 2);
        }
    };
    auto compute = [&](int buf) {
#pragma unroll
        for (int kk = 0; kk < 2; ++kk) {
            short8 af[4], bf[4];
#pragma unroll
            for (int i = 0; i < 4; ++i) {
                int m  = wm * 64 + i * 16 + l15;
                int cp = (kk * 4 + quad) ^ (m & 7);
                af[i]  = *(const short8*)(Al[buf] + m * 64 + cp * 8);
            }
#pragma unroll
            for (int j = 0; j < 4; ++j) {
                int n  = wn * 64 + j * 16 + l15;
                int cp = (kk * 4 + quad) ^ (n & 7);
                bf[j]  = *(const short8*)(Bl[buf] + n * 64 + cp * 8);
            }
#pragma unroll
            for (int i = 0; i < 4; ++i)
#pragma unroll
                for (int j = 0; j < 4; ++j)
                    acc[i][j] = __builtin_amdgcn_mfma_f32_16x16x32_bf16(af[i], bf[j], acc[i][j], 0, 0, 0);
        }
    };

    stage(0, 0);
    __syncthreads();
    for (int kt = 0; kt < 16; kt += 2) {
        if (kt + 1 < 16) stage(1, (kt + 1) * 64);
        compute(0);
        __syncthreads();
        if (kt + 2 < 16) stage(0, (kt + 2) * 64);
        compute(1);
        __syncthreads();
    }

#pragma unroll
    for (int j = 0; j < 4; ++j) {
        int n = n0 + wn * 64 + j * 16 + l15;
        float bb = bo[n];
#pragma unroll
        for (int i = 0; i < 4; ++i) {
            int m = m0 + wm * 64 + i * 16 + quad * 4;
#pragma unroll
            for (int r = 0; r < 4; ++r)
                out[(m + r) * 1024 + n] = acc[i][j][r] + bb;
        }
    }
}

// ---------------------------------------------------------------------------
extern "C" void kernel_launch(void* const* d_in, const int* in_sizes, int n_in,
                              void* d_out, int out_size, void* d_ws, size_t ws_size,
                              hipStream_t stream) {
    (void)in_sizes; (void)n_in; (void)out_size; (void)ws_size;
    const float* q_in = (const float*)d_in[0];
    const float* s_in = (const float*)d_in[1];
    const float* mask = (const float*)d_in[2];
    const float* Wq   = (const float*)d_in[3];
    const float* bq   = (const float*)d_in[4];
    const float* Wk   = (const float*)d_in[5];
    const float* bk   = (const float*)d_in[6];
    const float* Wv   = (const float*)d_in[7];
    const float* bv   = (const float*)d_in[8];
    const float* Wo   = (const float*)d_in[9];
    const float* bo   = (const float*)d_in[10];
    float* out = (float*)d_out;

    char* ws = (char*)d_ws;
    size_t off = 0;
    auto alloc = [&](size_t bytes) {
        char* p = ws + off;
        off += (bytes + 255) & ~(size_t)255;
        return p;
    };
    unsigned short* xqp = (unsigned short*)alloc((size_t)B_ * 2050 * 1024 * 2);
    unsigned short* xsp = (unsigned short*)alloc((size_t)B_ * 2050 * 1024 * 2);
    unsigned short* Wqt = (unsigned short*)alloc((size_t)KC_ * H_ * 2);
    unsigned short* Wkt = (unsigned short*)alloc((size_t)KC_ * H_ * 2);
    unsigned short* Wvt = (unsigned short*)alloc((size_t)KC_ * H_ * 2);
    unsigned short* Wot = (unsigned short*)alloc((size_t)H_ * H_ * 2);
    unsigned short* Qb  = (unsigned short*)alloc((size_t)B_ * NH_ * S_ * D_ * 2);
    unsigned short* Kb  = (unsigned short*)alloc((size_t)B_ * NH_ * S_ * D_ * 2);
    unsigned short* Vtb = (unsigned short*)alloc((size_t)B_ * NH_ * S_ * D_ * 2);
    unsigned short* Ab  = (unsigned short*)alloc((size_t)B_ * S_ * H_ * 2);

    k_pad_convert<<<4100, 256, 0, stream>>>(q_in, xqp);
    k_pad_convert<<<4100, 256, 0, stream>>>(s_in, xsp);
    k_transpose_bf16<<<dim3(32, 96), dim3(32, 8), 0, stream>>>(Wq, Wqt, KC_, H_);
    k_transpose_bf16<<<dim3(32, 96), dim3(32, 8), 0, stream>>>(Wk, Wkt, KC_, H_);
    k_transpose_bf16<<<dim3(32, 96), dim3(32, 8), 0, stream>>>(Wv, Wvt, KC_, H_);
    k_transpose_bf16<<<dim3(32, 32), dim3(32, 8), 0, stream>>>(Wo, Wot, H_, H_);
    k_conv_gemm<<<dim3(4, 16, 3), 512, 0, stream>>>(xqp, xsp, Wqt, Wkt, Wvt,
                                                    bq, bk, bv, Qb, Kb, Vtb);
    k_flash<<<dim3(16, 32), 256, 0, stream>>>(Qb, Kb, Vtb, mask, Ab);
    k_proj_gemm<<<dim3(8, 32), 256, 0, stream>>>(Ab, Wot, bo, out);
}